// Round 10
// baseline (120.182 us; speedup 1.0000x reference)
//
#include <hip/hip_runtime.h>
#include <math.h>

#define IN_CH 64
#define OUT_CH 64
#define M1 32
#define M2 32
#define HH 512
#define WW 512

// ---------------- workspace layout (floats) ----------------
// F   : [512][64]  cols 0..31 = cos(2pi k h/512), cols 32..63 = sin(...)
// FA2 : [256][64]  folded stage-A table. col j<32: re, j>=32: im; mode k=kperm(j&31);
//                  value = cos(2pi k w'/512) (re) or -sin (im). kperm(q)= q<16 ? 2q : 2(q-16)+1.
// GE2 : [64][256]  folded stage-E table. row c: c<16 re k=2c; 16..31 im k=2(c-16);
//                  32..47 re k=2(c-32)+1; 48..63 im k=2(c-48)+1. cos (re) / -sin (im).
// Xw0 : [32768][64] partial folded w-DFT (w'-half 0), cols ky'-ordered
// Xw1 : same, half 1
// XFp : [64 i][8 ht][2 reim][32 kx][32 ky']  partial h-DFT
// Gp  : [2 ic][64 o][32 kx][32 ky][2]  partial channel-mix (REAL ky order)
static const size_t OFF_F   = 0;
static const size_t OFF_FA2 = 32768;
static const size_t OFF_GE2 = 49152;
static const size_t OFF_XW0 = 65536;
static const size_t OFF_XW1 = OFF_XW0 + (size_t)32768*64;
static const size_t OFF_XFP = OFF_XW1 + (size_t)32768*64;
static const size_t OFF_GP  = OFF_XFP + (size_t)64*8*2048;

__global__ void build_table(float* __restrict__ F, float* __restrict__ FA2,
                            float* __restrict__ GE2) {
    int idx = blockIdx.x * 256 + threadIdx.x;      // 0..32767
    const float c0 = 6.283185307179586f / 512.0f;
    {   // F
        int w = idx >> 6, j = idx & 63, k = j & 31;
        int m = (k * w) & 511;
        float s, c;
        sincosf(c0 * (float)m, &s, &c);
        F[idx] = (j < 32) ? c : s;
    }
    if (idx < 16384) {   // FA2 [256][64]
        int wp = idx >> 6, j = idx & 63, q = j & 31;
        int k = (q < 16) ? 2 * q : 2 * (q - 16) + 1;
        int m = (k * wp) & 511;
        float s, c;
        sincosf(c0 * (float)m, &s, &c);
        FA2[idx] = (j < 32) ? c : -s;
    }
    if (idx < 16384) {   // GE2 [64][256]
        int cc = idx >> 8, wp = idx & 255;
        int base = cc & 15, parity = (cc >> 5) & 1, isIm = (cc >> 4) & 1;
        int k = 2 * base + parity;
        int m = (k * wp) & 511;
        float s, c;
        sincosf(c0 * (float)m, &s, &c);
        GE2[idx] = isIm ? -s : c;
    }
}

// Stage A, LDS-free / barrier-free: Xw[row][j'] = sum_{w'} (x[w'] +/- x[w'+256]) * FA2[w'][j']
// grid 1024: rb = bid>>1 (64-row tile), kh = bid&1 (w'-half of 128, partial sums).
// A-side reads are 16-lane broadcasts (1 sector), B-side FA2 is L1/L2-hot: zero LDS traffic.
__global__ __launch_bounds__(256) void gemmA(const float* __restrict__ x,
                                             const float* __restrict__ FA2,
                                             float* __restrict__ Xw0,
                                             float* __restrict__ Xw1) {
    int t = threadIdx.x, tx = t & 15, ty = t >> 4;
    int rb = blockIdx.x >> 1, kh = blockIdx.x & 1;
    int rowBase = rb * 64;
    int kbase = kh * 128;
    bool odd = (tx & 4) != 0;                      // cols 16..31,48..63 use o = a-b

    const float* xr0 = x + (size_t)(rowBase + ty * 4 + 0) * 512 + kbase;
    const float* xr1 = x + (size_t)(rowBase + ty * 4 + 1) * 512 + kbase;
    const float* xr2 = x + (size_t)(rowBase + ty * 4 + 2) * 512 + kbase;
    const float* xr3 = x + (size_t)(rowBase + ty * 4 + 3) * 512 + kbase;
    const float* fb  = FA2 + (size_t)kbase * 64 + tx * 4;

    float acc[4][4] = {};
#pragma unroll 2
    for (int k0 = 0; k0 < 128; k0 += 4) {
        float4 pa[4], pb[4], bv[4];
        pa[0] = *(const float4*)(xr0 + k0); pb[0] = *(const float4*)(xr0 + k0 + 256);
        pa[1] = *(const float4*)(xr1 + k0); pb[1] = *(const float4*)(xr1 + k0 + 256);
        pa[2] = *(const float4*)(xr2 + k0); pb[2] = *(const float4*)(xr2 + k0 + 256);
        pa[3] = *(const float4*)(xr3 + k0); pb[3] = *(const float4*)(xr3 + k0 + 256);
#pragma unroll
        for (int kk = 0; kk < 4; ++kk)
            bv[kk] = *(const float4*)(fb + (size_t)(k0 + kk) * 64);
        float4 a[4];
#pragma unroll
        for (int r = 0; r < 4; ++r)
            a[r] = odd ? make_float4(pa[r].x - pb[r].x, pa[r].y - pb[r].y,
                                     pa[r].z - pb[r].z, pa[r].w - pb[r].w)
                       : make_float4(pa[r].x + pb[r].x, pa[r].y + pb[r].y,
                                     pa[r].z + pb[r].z, pa[r].w + pb[r].w);
#pragma unroll
        for (int kk = 0; kk < 4; ++kk)
#pragma unroll
            for (int r = 0; r < 4; ++r) {
                float xk = (kk == 0) ? a[r].x : (kk == 1) ? a[r].y
                         : (kk == 2) ? a[r].z : a[r].w;
                acc[r][0] = __builtin_fmaf(xk, bv[kk].x, acc[r][0]);
                acc[r][1] = __builtin_fmaf(xk, bv[kk].y, acc[r][1]);
                acc[r][2] = __builtin_fmaf(xk, bv[kk].z, acc[r][2]);
                acc[r][3] = __builtin_fmaf(xk, bv[kk].w, acc[r][3]);
            }
    }
    float* Cb = (kh ? Xw1 : Xw0) + (size_t)rowBase * 64;
#pragma unroll
    for (int r = 0; r < 4; ++r)
        *(float4*)&Cb[(size_t)(ty * 4 + r) * 64 + tx * 4] =
            make_float4(acc[r][0], acc[r][1], acc[r][2], acc[r][3]);
}

// Stage B, LDS-free: XFp[i][ht][re/im][kx][ky'] = sum_{hh<64} Xw[i,h0+hh,ky']*e^{-2pi i kx h/512}
// grid 512: i = bid>>3, ht = bid&7. thread: kx = t&31 (lane), jq = t>>5 (ky'-quad).
// Xw reads are broadcast VMEM (L2-hot), cv/sv coalesced from F.
__global__ __launch_bounds__(256) void stageB2(const float* __restrict__ Xw0,
                                               const float* __restrict__ Xw1,
                                               const float* __restrict__ F,
                                               float* __restrict__ XFp) {
    int t = threadIdx.x;
    int kx = t & 31, jq = t >> 5;          // jq 0..7 -> ky' quad jq*4..+3
    int i = blockIdx.x >> 3, ht = blockIdx.x & 7;
    int h0 = ht * 64;

    float rr[4] = {0.f, 0.f, 0.f, 0.f};
    float ii[4] = {0.f, 0.f, 0.f, 0.f};
    const float* xw0b = Xw0 + ((size_t)i * 512 + h0) * 64 + jq * 4;
    const float* xw1b = Xw1 + ((size_t)i * 512 + h0) * 64 + jq * 4;
    const float* fbb  = F + (size_t)h0 * 64 + kx;

    for (int hh = 0; hh < 64; ++hh) {
        float4 ra0 = *(const float4*)(xw0b + hh * 64);
        float4 ra1 = *(const float4*)(xw1b + hh * 64);
        float4 rb0 = *(const float4*)(xw0b + hh * 64 + 32);
        float4 rb1 = *(const float4*)(xw1b + hh * 64 + 32);
        float4 xr = make_float4(ra0.x + ra1.x, ra0.y + ra1.y, ra0.z + ra1.z, ra0.w + ra1.w);
        float4 xi = make_float4(rb0.x + rb1.x, rb0.y + rb1.y, rb0.z + rb1.z, rb0.w + rb1.w);
        float cv = fbb[hh * 64];
        float sv = fbb[hh * 64 + 32];
        // Re = xr*c + xi*s ; Im = xi*c - xr*s
        rr[0] = __builtin_fmaf(xr.x, cv, rr[0]); rr[0] = __builtin_fmaf(xi.x, sv, rr[0]);
        rr[1] = __builtin_fmaf(xr.y, cv, rr[1]); rr[1] = __builtin_fmaf(xi.y, sv, rr[1]);
        rr[2] = __builtin_fmaf(xr.z, cv, rr[2]); rr[2] = __builtin_fmaf(xi.z, sv, rr[2]);
        rr[3] = __builtin_fmaf(xr.w, cv, rr[3]); rr[3] = __builtin_fmaf(xi.w, sv, rr[3]);
        ii[0] = __builtin_fmaf(xi.x, cv, ii[0]); ii[0] = __builtin_fmaf(-xr.x, sv, ii[0]);
        ii[1] = __builtin_fmaf(xi.y, cv, ii[1]); ii[1] = __builtin_fmaf(-xr.y, sv, ii[1]);
        ii[2] = __builtin_fmaf(xi.z, cv, ii[2]); ii[2] = __builtin_fmaf(-xr.z, sv, ii[2]);
        ii[3] = __builtin_fmaf(xi.w, cv, ii[3]); ii[3] = __builtin_fmaf(-xr.w, sv, ii[3]);
    }
    size_t base = ((size_t)i * 8 + ht) * 2048 + kx * 32 + jq * 4;
    *(float4*)&XFp[base]        = make_float4(rr[0], rr[1], rr[2], rr[3]);
    *(float4*)&XFp[base + 1024] = make_float4(ii[0], ii[1], ii[2], ii[3]);
}

// Stage C: partial channel mix, i split in 2. grid 512. (unchanged, verified)
__global__ __launch_bounds__(256) void stageC(const float* __restrict__ XFp,
                                              const float* __restrict__ Wr,
                                              const float* __restrict__ Wi,
                                              float* __restrict__ Gp) {
    __shared__ float sxr[32][33];   // [ky'][i']
    __shared__ float sxi[32][33];
    int t = threadIdx.x;
    int kx = blockIdx.x & 31, oc = (blockIdx.x >> 5) & 7, ic = blockIdx.x >> 8;
#pragma unroll
    for (int q = 0; q < 4; ++q) {
        int idx = q * 256 + t;               // 0..1023 = i'*32 + ky'(storage)
        int ip = idx >> 5, kys = idx & 31;
        int i = ic * 32 + ip;
        float sr = 0.f, si = 0.f;
#pragma unroll
        for (int ht = 0; ht < 8; ++ht) {
            size_t base = ((size_t)i * 8 + ht) * 2048 + kx * 32 + kys;
            sr += XFp[base];
            si += XFp[base + 1024];
        }
        sxr[kys][ip] = sr;
        sxi[kys][ip] = si;
    }
    __syncthreads();
    int ky = t & 31, ol = t >> 5;            // REAL ky
    int kyp = (ky & 1) ? 16 + (ky >> 1) : (ky >> 1);
    int o = oc * 8 + ol;
    float lr = 0.f, li = 0.f;
#pragma unroll 4
    for (int ip = 0; ip < 32; ++ip) {
        float a = sxr[kyp][ip];
        float b = sxi[kyp][ip];
        size_t widx = ((size_t)(ic * 32 + ip) * 64 + o) * 1024 + kx * 32 + ky;
        float wrv = Wr[widx];
        float wiv = Wi[widx];
        lr = __builtin_fmaf(a, wrv, lr); lr = __builtin_fmaf(-b, wiv, lr);
        li = __builtin_fmaf(a, wiv, li); li = __builtin_fmaf(b, wrv, li);
    }
    size_t gidx = ((size_t)ic * 65536 + (size_t)o * 1024 + kx * 32 + ky) * 2;
    Gp[gidx]     = lr;
    Gp[gidx + 1] = li;
}

// Fused (reduceG +) D + E. grid 512: o = bid>>3, ht = bid&7.
// D A-side (F) and E B-side (GE2) now come straight from VMEM (L1/L2-hot tables);
// LDS holds only G (block-built) and the Z transpose. 2 barriers total.
__global__ __launch_bounds__(256) void fusedDE(const float* __restrict__ Fc,
                                               const float* __restrict__ Gp,
                                               const float* __restrict__ GE2,
                                               float* __restrict__ out) {
    __shared__ __align__(16) float as[4096];   // Z (XOR-swizzled)
    __shared__ __align__(16) float bs[4096];   // G [64m][64j']
    int t = threadIdx.x, tx = t & 15, ty = t >> 4;
    int o = blockIdx.x >> 3, ht = blockIdx.x & 7;
    int h0 = ht * 64;
    int sw = (ty & 3) << 2;

    // build G[o] into bs (reduce 2 i-partials, scale, sign-expand, parity-grouped cols)
    const float2* gp2 = (const float2*)Gp;
#pragma unroll
    for (int q = 0; q < 4; ++q) {
        int iq = q * 256 + t;                 // 0..1023 = kx*32+ky (REAL ky)
        int ky = iq & 31, kx = iq >> 5;
        float2 g0 = gp2[(size_t)o * 1024 + iq];
        float2 g1 = gp2[(size_t)65536 + (size_t)o * 1024 + iq];
        float sc = ((ky == 0) ? 1.0f : 2.0f) * (1.0f / 262144.0f);
        float lr = (g0.x + g1.x) * sc;
        float li = (g0.y + g1.y) * sc;
        int pp = ky & 1, qq = ky >> 1;
        int colR = pp * 32 + qq, colI = pp * 32 + 16 + qq;
        bs[kx * 64 + colR]        = lr;
        bs[(32 + kx) * 64 + colR] = -li;
        bs[kx * 64 + colI]        = li;
        bs[(32 + kx) * 64 + colI] = lr;
    }
    __syncthreads();

    // D inner: Z[row][j'] = sum_m F[h0+row][m] * G[m][j'] ; F via broadcast VMEM
    float acc[4][4] = {};
    const float* f0 = Fc + (size_t)(h0 + ty * 4 + 0) * 64;
    const float* f1 = Fc + (size_t)(h0 + ty * 4 + 1) * 64;
    const float* f2 = Fc + (size_t)(h0 + ty * 4 + 2) * 64;
    const float* f3 = Fc + (size_t)(h0 + ty * 4 + 3) * 64;
#pragma unroll 4
    for (int k0 = 0; k0 < 64; k0 += 4) {
        float4 av[4], bv[4];
        av[0] = *(const float4*)(f0 + k0);
        av[1] = *(const float4*)(f1 + k0);
        av[2] = *(const float4*)(f2 + k0);
        av[3] = *(const float4*)(f3 + k0);
#pragma unroll
        for (int kk = 0; kk < 4; ++kk)
            bv[kk] = *(const float4*)&bs[(k0 + kk) * 64 + tx * 4];
#pragma unroll
        for (int kk = 0; kk < 4; ++kk)
#pragma unroll
            for (int r = 0; r < 4; ++r) {
                float xk = (kk == 0) ? av[r].x : (kk == 1) ? av[r].y
                         : (kk == 2) ? av[r].z : av[r].w;
                acc[r][0] = __builtin_fmaf(xk, bv[kk].x, acc[r][0]);
                acc[r][1] = __builtin_fmaf(xk, bv[kk].y, acc[r][1]);
                acc[r][2] = __builtin_fmaf(xk, bv[kk].z, acc[r][2]);
                acc[r][3] = __builtin_fmaf(xk, bv[kk].w, acc[r][3]);
            }
    }

    // store Z into as with XOR swizzle (matches E's read pattern)
#pragma unroll
    for (int r = 0; r < 4; ++r) {
        int row = ty * 4 + r;
        int cg = tx ^ ((row >> 2) & 3);
        *(float4*)&as[row * 64 + cg * 4] =
            make_float4(acc[r][0], acc[r][1], acc[r][2], acc[r][3]);
    }
    __syncthreads();

    // E: P = Z[:,0..31] x GE2 rows 0..31, Q = Z[:,32..63] x GE2 rows 32..63
    // out[w'] = P+Q, out[w'+256] = P-Q. GE2 via VMEM; no barriers in cb loop.
    for (int cb = 0; cb < 4; ++cb) {
        const float* geb = GE2 + cb * 64 + tx * 4;
        float pa[4][4] = {}, pb[4][4] = {};
#pragma unroll 4
        for (int k0 = 0; k0 < 32; k0 += 4) {
            int kae = k0 ^ sw, kao = 32 + (k0 ^ sw);
            float4 av[4], bv[4], aw[4], bw[4];
#pragma unroll
            for (int r = 0; r < 4; ++r) {
                av[r] = *(const float4*)&as[(ty * 4 + r) * 64 + kae];
                aw[r] = *(const float4*)&as[(ty * 4 + r) * 64 + kao];
            }
#pragma unroll
            for (int kk = 0; kk < 4; ++kk) {
                bv[kk] = *(const float4*)(geb + (size_t)(k0 + kk) * 256);
                bw[kk] = *(const float4*)(geb + (size_t)(32 + k0 + kk) * 256);
            }
#pragma unroll
            for (int kk = 0; kk < 4; ++kk)
#pragma unroll
                for (int r = 0; r < 4; ++r) {
                    float xe = (kk == 0) ? av[r].x : (kk == 1) ? av[r].y
                             : (kk == 2) ? av[r].z : av[r].w;
                    float xo = (kk == 0) ? aw[r].x : (kk == 1) ? aw[r].y
                             : (kk == 2) ? aw[r].z : aw[r].w;
                    pa[r][0] = __builtin_fmaf(xe, bv[kk].x, pa[r][0]);
                    pa[r][1] = __builtin_fmaf(xe, bv[kk].y, pa[r][1]);
                    pa[r][2] = __builtin_fmaf(xe, bv[kk].z, pa[r][2]);
                    pa[r][3] = __builtin_fmaf(xe, bv[kk].w, pa[r][3]);
                    pb[r][0] = __builtin_fmaf(xo, bw[kk].x, pb[r][0]);
                    pb[r][1] = __builtin_fmaf(xo, bw[kk].y, pb[r][1]);
                    pb[r][2] = __builtin_fmaf(xo, bw[kk].z, pb[r][2]);
                    pb[r][3] = __builtin_fmaf(xo, bw[kk].w, pb[r][3]);
                }
        }
#pragma unroll
        for (int r = 0; r < 4; ++r) {
            float* orow = out + (size_t)(o * 512 + h0 + ty * 4 + r) * 512;
            *(float4*)&orow[cb * 64 + tx * 4] =
                make_float4(pa[r][0] + pb[r][0], pa[r][1] + pb[r][1],
                            pa[r][2] + pb[r][2], pa[r][3] + pb[r][3]);
            *(float4*)&orow[256 + cb * 64 + tx * 4] =
                make_float4(pa[r][0] - pb[r][0], pa[r][1] - pb[r][1],
                            pa[r][2] - pb[r][2], pa[r][3] - pb[r][3]);
        }
    }
}

extern "C" void kernel_launch(void* const* d_in, const int* in_sizes, int n_in,
                              void* d_out, int out_size, void* d_ws, size_t ws_size,
                              hipStream_t stream) {
    const float* x  = (const float*)d_in[0];
    const float* Wr = (const float*)d_in[1];
    const float* Wi = (const float*)d_in[2];
    float* out = (float*)d_out;
    float* ws  = (float*)d_ws;

    float* F   = ws + OFF_F;
    float* FA2 = ws + OFF_FA2;
    float* GE2 = ws + OFF_GE2;
    float* Xw0 = ws + OFF_XW0;
    float* Xw1 = ws + OFF_XW1;
    float* XFp = ws + OFF_XFP;
    float* Gp  = ws + OFF_GP;

    build_table<<<128, 256, 0, stream>>>(F, FA2, GE2);
    gemmA<<<1024, 256, 0, stream>>>(x, FA2, Xw0, Xw1);
    stageB2<<<512, 256, 0, stream>>>(Xw0, Xw1, F, XFp);
    stageC<<<512, 256, 0, stream>>>(XFp, Wr, Wi, Gp);
    fusedDE<<<512, 256, 0, stream>>>(F, Gp, GE2, out);
}

// Round 11
// 108.970 us; speedup vs baseline: 1.1029x; 1.1029x over previous
//
#include <hip/hip_runtime.h>
#include <math.h>

#define IN_CH 64
#define OUT_CH 64
#define M1 32
#define M2 32
#define HH 512
#define WW 512

// ---------------- workspace layout (floats) ----------------
// F   : [512][64]  cols 0..31 = cos(2pi k h/512), cols 32..63 = sin(...)
// FA2 : [256][64]  folded stage-A table. col j<32: re, j>=32: im; mode k=kperm(j&31);
//                  value = cos(2pi k w'/512) (re) or -sin (im). kperm(q)= q<16 ? 2q : 2(q-16)+1.
// GE2 : [64][256]  folded stage-E table. row c: c<16 re k=2c; 16..31 im k=2(c-16);
//                  32..47 re k=2(c-32)+1; 48..63 im k=2(c-48)+1. cos (re) / -sin (im).
// XFp : [64 i][16 ht][2 reim][32 kx][32 ky']  partial h-DFT (32-row h-tiles)
// Gp  : [2 ic][64 o][32 kx][32 ky][2]  partial channel-mix (REAL ky order)
static const size_t OFF_F   = 0;
static const size_t OFF_FA2 = 32768;
static const size_t OFF_GE2 = 49152;
static const size_t OFF_XFP = 65536;
static const size_t OFF_GP  = OFF_XFP + (size_t)64*16*2048;

__device__ __forceinline__ void gload16(const float* g, float* l) {
    __builtin_amdgcn_global_load_lds(
        (const __attribute__((address_space(1))) void*)g,
        (__attribute__((address_space(3))) void*)l, 16, 0, 0);
}

__global__ void build_table(float* __restrict__ F, float* __restrict__ FA2,
                            float* __restrict__ GE2) {
    int idx = blockIdx.x * 256 + threadIdx.x;      // 0..32767
    const float c0 = 6.283185307179586f / 512.0f;
    {   // F
        int w = idx >> 6, j = idx & 63, k = j & 31;
        int m = (k * w) & 511;
        float s, c;
        sincosf(c0 * (float)m, &s, &c);
        F[idx] = (j < 32) ? c : s;
    }
    if (idx < 16384) {   // FA2 [256][64]
        int wp = idx >> 6, j = idx & 63, q = j & 31;
        int k = (q < 16) ? 2 * q : 2 * (q - 16) + 1;
        int m = (k * wp) & 511;
        float s, c;
        sincosf(c0 * (float)m, &s, &c);
        FA2[idx] = (j < 32) ? c : -s;
    }
    if (idx < 16384) {   // GE2 [64][256]
        int cc = idx >> 8, wp = idx & 255;
        int base = cc & 15, parity = (cc >> 5) & 1, isIm = (cc >> 4) & 1;
        int k = 2 * base + parity;
        int m = (k * wp) & 511;
        float s, c;
        sincosf(c0 * (float)m, &s, &c);
        GE2[idx] = isIm ? -s : c;
    }
}

// Fused A+B, BM=32. grid 1024: i = bid>>4, ht = bid&15 (32 h-rows).
// A: Xw[32][64 j'] = sum_{w'<256} eo[w'] * FA2[w'][j'] ; FA2 via VMEM (L1-hot),
//    x parity-folded in LDS, acc[1][8] per thread -> 1 LDS b128 per k-quad.
// B: XFp partial over 32 hh; 2x2 (kx,ky) register blocking -> 4 b64 per 16 FMA.
__global__ __launch_bounds__(256, 4) void fusedAB(const float* __restrict__ x,
                                                  const float* __restrict__ FA2,
                                                  const float* __restrict__ F,
                                                  float* __restrict__ XFp) {
    __shared__ __align__(16) float xeo[4352];   // e/xw [32][68] @0 ; o/gtT [32][68] @2176
    int t = threadIdx.x;
    int i = blockIdx.x >> 4, ht = blockIdx.x & 15;
    int h0 = ht * 32;
    int srow = t >> 3, scol = (t & 7) * 8;      // staging AND compute map (row, col-octet)
    int tx8 = t & 7, c8 = tx8 * 8;
    const float* xsb = &xeo[((tx8 >> 1) & 1) ? 2176 : 0] + srow * 68;  // odd-k cols read o

    const float* xb = x + ((size_t)i * 512 + h0 + srow) * 512 + scol;

    float acc[8] = {};
    for (int tt = 0; tt < 4; ++tt) {
        const float* xt = xb + tt * 64;
        float4 a0 = *(const float4*)(xt);
        float4 a1 = *(const float4*)(xt + 4);
        float4 b0 = *(const float4*)(xt + 256);
        float4 b1 = *(const float4*)(xt + 260);
        if (tt) __syncthreads();               // readers of previous tile done
        *(float4*)&xeo[srow * 68 + scol] =
            make_float4(a0.x + b0.x, a0.y + b0.y, a0.z + b0.z, a0.w + b0.w);
        *(float4*)&xeo[srow * 68 + scol + 4] =
            make_float4(a1.x + b1.x, a1.y + b1.y, a1.z + b1.z, a1.w + b1.w);
        *(float4*)&xeo[2176 + srow * 68 + scol] =
            make_float4(a0.x - b0.x, a0.y - b0.y, a0.z - b0.z, a0.w - b0.w);
        *(float4*)&xeo[2176 + srow * 68 + scol + 4] =
            make_float4(a1.x - b1.x, a1.y - b1.y, a1.z - b1.z, a1.w - b1.w);
        __syncthreads();                       // tile visible
        const float* fb = FA2 + (size_t)(tt * 64) * 64 + c8;
#pragma unroll 2
        for (int k0 = 0; k0 < 64; k0 += 4) {
            float4 av = *(const float4*)(xsb + k0);
#pragma unroll
            for (int kk = 0; kk < 4; ++kk) {
                float4 bv0 = *(const float4*)(fb + (size_t)(k0 + kk) * 64);
                float4 bv1 = *(const float4*)(fb + (size_t)(k0 + kk) * 64 + 4);
                float xk = (kk == 0) ? av.x : (kk == 1) ? av.y
                         : (kk == 2) ? av.z : av.w;
                acc[0] = __builtin_fmaf(xk, bv0.x, acc[0]);
                acc[1] = __builtin_fmaf(xk, bv0.y, acc[1]);
                acc[2] = __builtin_fmaf(xk, bv0.z, acc[2]);
                acc[3] = __builtin_fmaf(xk, bv0.w, acc[3]);
                acc[4] = __builtin_fmaf(xk, bv1.x, acc[4]);
                acc[5] = __builtin_fmaf(xk, bv1.y, acc[5]);
                acc[6] = __builtin_fmaf(xk, bv1.z, acc[6]);
                acc[7] = __builtin_fmaf(xk, bv1.w, acc[7]);
            }
        }
    }
    __syncthreads();   // all xeo readers done

    // store Xw into e-part; stage trig rows (F[h0..h0+31][0..63]) into o-part
    *(float4*)&xeo[srow * 68 + c8]     = make_float4(acc[0], acc[1], acc[2], acc[3]);
    *(float4*)&xeo[srow * 68 + c8 + 4] = make_float4(acc[4], acc[5], acc[6], acc[7]);
    float4 f0 = *(const float4*)&F[(size_t)(h0 + srow) * 64 + scol];
    float4 f1 = *(const float4*)&F[(size_t)(h0 + srow) * 64 + scol + 4];
    *(float4*)&xeo[2176 + srow * 68 + scol]     = f0;
    *(float4*)&xeo[2176 + srow * 68 + scol + 4] = f1;
    __syncthreads();

    // Phase B: kxp = t>>4 (kx pair), kyp = t&15 (ky' pair)
    int kxp = t >> 4, kyp = t & 15;
    const float* xwb = &xeo[2 * kyp];
    const float* gtb = &xeo[2176 + 2 * kxp];
    float rr00 = 0.f, rr01 = 0.f, rr10 = 0.f, rr11 = 0.f;
    float ii00 = 0.f, ii01 = 0.f, ii10 = 0.f, ii11 = 0.f;
#pragma unroll 4
    for (int hh = 0; hh < 32; ++hh) {
        float2 xr = *(const float2*)(xwb + hh * 68);
        float2 xi = *(const float2*)(xwb + hh * 68 + 32);
        float2 cv = *(const float2*)(gtb + hh * 68);
        float2 sv = *(const float2*)(gtb + hh * 68 + 32);
        // Re += xr*c + xi*s ; Im += xi*c - xr*s
        rr00 = __builtin_fmaf(xr.x, cv.x, rr00); rr00 = __builtin_fmaf(xi.x, sv.x, rr00);
        rr01 = __builtin_fmaf(xr.y, cv.x, rr01); rr01 = __builtin_fmaf(xi.y, sv.x, rr01);
        rr10 = __builtin_fmaf(xr.x, cv.y, rr10); rr10 = __builtin_fmaf(xi.x, sv.y, rr10);
        rr11 = __builtin_fmaf(xr.y, cv.y, rr11); rr11 = __builtin_fmaf(xi.y, sv.y, rr11);
        ii00 = __builtin_fmaf(xi.x, cv.x, ii00); ii00 = __builtin_fmaf(-xr.x, sv.x, ii00);
        ii01 = __builtin_fmaf(xi.y, cv.x, ii01); ii01 = __builtin_fmaf(-xr.y, sv.x, ii01);
        ii10 = __builtin_fmaf(xi.x, cv.y, ii10); ii10 = __builtin_fmaf(-xr.x, sv.y, ii10);
        ii11 = __builtin_fmaf(xi.y, cv.y, ii11); ii11 = __builtin_fmaf(-xr.y, sv.y, ii11);
    }
    size_t base = ((size_t)i * 16 + ht) * 2048;
    *(float2*)&XFp[base + (size_t)(2 * kxp + 0) * 32 + 2 * kyp] = make_float2(rr00, rr01);
    *(float2*)&XFp[base + (size_t)(2 * kxp + 1) * 32 + 2 * kyp] = make_float2(rr10, rr11);
    *(float2*)&XFp[base + 1024 + (size_t)(2 * kxp + 0) * 32 + 2 * kyp] = make_float2(ii00, ii01);
    *(float2*)&XFp[base + 1024 + (size_t)(2 * kxp + 1) * 32 + 2 * kyp] = make_float2(ii10, ii11);
}

// Stage C: partial channel mix, i split in 2. grid 512. (R7 structure, 16 ht partials)
__global__ __launch_bounds__(256) void stageC(const float* __restrict__ XFp,
                                              const float* __restrict__ Wr,
                                              const float* __restrict__ Wi,
                                              float* __restrict__ Gp) {
    __shared__ float sxr[32][33];   // [ky'][i']
    __shared__ float sxi[32][33];
    int t = threadIdx.x;
    int kx = blockIdx.x & 31, oc = (blockIdx.x >> 5) & 7, ic = blockIdx.x >> 8;
#pragma unroll
    for (int q = 0; q < 4; ++q) {
        int idx = q * 256 + t;               // 0..1023 = i'*32 + ky'(storage)
        int ip = idx >> 5, kys = idx & 31;
        int i = ic * 32 + ip;
        float sr = 0.f, si = 0.f;
#pragma unroll
        for (int htl = 0; htl < 16; ++htl) {
            size_t base = ((size_t)i * 16 + htl) * 2048 + kx * 32 + kys;
            sr += XFp[base];
            si += XFp[base + 1024];
        }
        sxr[kys][ip] = sr;
        sxi[kys][ip] = si;
    }
    __syncthreads();
    int ky = t & 31, ol = t >> 5;            // REAL ky
    int kyp = (ky & 1) ? 16 + (ky >> 1) : (ky >> 1);
    int o = oc * 8 + ol;
    float lr = 0.f, li = 0.f;
#pragma unroll 4
    for (int ip = 0; ip < 32; ++ip) {
        float a = sxr[kyp][ip];
        float b = sxi[kyp][ip];
        size_t widx = ((size_t)(ic * 32 + ip) * 64 + o) * 1024 + kx * 32 + ky;
        float wrv = Wr[widx];
        float wiv = Wi[widx];
        lr = __builtin_fmaf(a, wrv, lr); lr = __builtin_fmaf(-b, wiv, lr);
        li = __builtin_fmaf(a, wiv, li); li = __builtin_fmaf(b, wrv, li);
    }
    size_t gidx = ((size_t)ic * 65536 + (size_t)o * 1024 + kx * 32 + ky) * 2;
    Gp[gidx]     = lr;
    Gp[gidx + 1] = li;
}

// Fused (reduceG +) D + E. grid 512: o = bid>>3, ht = bid&7. (R7 verbatim)
__global__ __launch_bounds__(256) void fusedDE(const float* __restrict__ Fc,
                                               const float* __restrict__ Gp,
                                               const float* __restrict__ GE2,
                                               float* __restrict__ out) {
    __shared__ __align__(16) float as[4096];   // F-tile (src-swizzled), then Z (XOR-swizzled)
    __shared__ __align__(16) float bs[4096];   // G [64m][64j'], then GE2 tiles
    int t = threadIdx.x, tx = t & 15, ty = t >> 4;
    int o = blockIdx.x >> 3, ht = blockIdx.x & 7;
    int sw = (ty & 3) << 2;

    const float2* gp2 = (const float2*)Gp;
#pragma unroll
    for (int q = 0; q < 4; ++q) {
        int iq = q * 256 + t;                 // 0..1023 = kx*32+ky (REAL ky)
        int ky = iq & 31, kx = iq >> 5;
        float2 g0 = gp2[(size_t)o * 1024 + iq];
        float2 g1 = gp2[(size_t)65536 + (size_t)o * 1024 + iq];
        float sc = ((ky == 0) ? 1.0f : 2.0f) * (1.0f / 262144.0f);
        float lr = (g0.x + g1.x) * sc;
        float li = (g0.y + g1.y) * sc;
        int pp = ky & 1, qq = ky >> 1;
        int colR = pp * 32 + qq, colI = pp * 32 + 16 + qq;
        bs[kx * 64 + colR]        = lr;
        bs[(32 + kx) * 64 + colR] = -li;
        bs[kx * 64 + colI]        = li;
        bs[(32 + kx) * 64 + colI] = lr;
    }
#pragma unroll
    for (int p = 0; p < 4; ++p) {
        int flat = p * 1024 + t * 4;
        int s16 = flat >> 2;
        int row = s16 >> 4, cp = s16 & 15;
        int cg = cp ^ ((row >> 2) & 3);
        gload16(Fc + (size_t)(ht * 64 + row) * 64 + cg * 4, &as[flat]);
    }
    __syncthreads();

    float acc[4][4] = {};
#pragma unroll 4
    for (int k0 = 0; k0 < 64; k0 += 4) {
        int ka = k0 ^ sw;
        float4 av[4], bv[4];
#pragma unroll
        for (int r = 0; r < 4; ++r)
            av[r] = *(const float4*)&as[(ty * 4 + r) * 64 + ka];
#pragma unroll
        for (int kk = 0; kk < 4; ++kk)
            bv[kk] = *(const float4*)&bs[(k0 + kk) * 64 + tx * 4];
#pragma unroll
        for (int kk = 0; kk < 4; ++kk)
#pragma unroll
            for (int r = 0; r < 4; ++r) {
                float xk = (kk == 0) ? av[r].x : (kk == 1) ? av[r].y
                         : (kk == 2) ? av[r].z : av[r].w;
                acc[r][0] = __builtin_fmaf(xk, bv[kk].x, acc[r][0]);
                acc[r][1] = __builtin_fmaf(xk, bv[kk].y, acc[r][1]);
                acc[r][2] = __builtin_fmaf(xk, bv[kk].z, acc[r][2]);
                acc[r][3] = __builtin_fmaf(xk, bv[kk].w, acc[r][3]);
            }
    }
    __syncthreads();

#pragma unroll
    for (int r = 0; r < 4; ++r) {
        int row = ty * 4 + r;
        int cg = tx ^ ((row >> 2) & 3);
        *(float4*)&as[row * 64 + cg * 4] =
            make_float4(acc[r][0], acc[r][1], acc[r][2], acc[r][3]);
    }

    for (int cb = 0; cb < 4; ++cb) {
        __syncthreads();
#pragma unroll
        for (int p = 0; p < 4; ++p) {
            int flat = p * 1024 + t * 4;
            int brow = flat >> 6, bcol = flat & 63;
            gload16(GE2 + (size_t)brow * 256 + cb * 64 + bcol, &bs[flat]);
        }
        __syncthreads();
        float pa[4][4] = {}, pb[4][4] = {};
#pragma unroll 4
        for (int k0 = 0; k0 < 32; k0 += 4) {
            int kae = k0 ^ sw, kao = 32 + (k0 ^ sw);
            float4 av[4], bv[4], aw[4], bw[4];
#pragma unroll
            for (int r = 0; r < 4; ++r) {
                av[r] = *(const float4*)&as[(ty * 4 + r) * 64 + kae];
                aw[r] = *(const float4*)&as[(ty * 4 + r) * 64 + kao];
            }
#pragma unroll
            for (int kk = 0; kk < 4; ++kk) {
                bv[kk] = *(const float4*)&bs[(k0 + kk) * 64 + tx * 4];
                bw[kk] = *(const float4*)&bs[(32 + k0 + kk) * 64 + tx * 4];
            }
#pragma unroll
            for (int kk = 0; kk < 4; ++kk)
#pragma unroll
                for (int r = 0; r < 4; ++r) {
                    float xe = (kk == 0) ? av[r].x : (kk == 1) ? av[r].y
                             : (kk == 2) ? av[r].z : av[r].w;
                    float xo = (kk == 0) ? aw[r].x : (kk == 1) ? aw[r].y
                             : (kk == 2) ? aw[r].z : aw[r].w;
                    pa[r][0] = __builtin_fmaf(xe, bv[kk].x, pa[r][0]);
                    pa[r][1] = __builtin_fmaf(xe, bv[kk].y, pa[r][1]);
                    pa[r][2] = __builtin_fmaf(xe, bv[kk].z, pa[r][2]);
                    pa[r][3] = __builtin_fmaf(xe, bv[kk].w, pa[r][3]);
                    pb[r][0] = __builtin_fmaf(xo, bw[kk].x, pb[r][0]);
                    pb[r][1] = __builtin_fmaf(xo, bw[kk].y, pb[r][1]);
                    pb[r][2] = __builtin_fmaf(xo, bw[kk].z, pb[r][2]);
                    pb[r][3] = __builtin_fmaf(xo, bw[kk].w, pb[r][3]);
                }
        }
#pragma unroll
        for (int r = 0; r < 4; ++r) {
            float* orow = out + (size_t)(o * 512 + ht * 64 + ty * 4 + r) * 512;
            *(float4*)&orow[cb * 64 + tx * 4] =
                make_float4(pa[r][0] + pb[r][0], pa[r][1] + pb[r][1],
                            pa[r][2] + pb[r][2], pa[r][3] + pb[r][3]);
            *(float4*)&orow[256 + cb * 64 + tx * 4] =
                make_float4(pa[r][0] - pb[r][0], pa[r][1] - pb[r][1],
                            pa[r][2] - pb[r][2], pa[r][3] - pb[r][3]);
        }
    }
}

extern "C" void kernel_launch(void* const* d_in, const int* in_sizes, int n_in,
                              void* d_out, int out_size, void* d_ws, size_t ws_size,
                              hipStream_t stream) {
    const float* x  = (const float*)d_in[0];
    const float* Wr = (const float*)d_in[1];
    const float* Wi = (const float*)d_in[2];
    float* out = (float*)d_out;
    float* ws  = (float*)d_ws;

    float* F   = ws + OFF_F;
    float* FA2 = ws + OFF_FA2;
    float* GE2 = ws + OFF_GE2;
    float* XFp = ws + OFF_XFP;
    float* Gp  = ws + OFF_GP;

    build_table<<<128, 256, 0, stream>>>(F, FA2, GE2);
    fusedAB<<<1024, 256, 0, stream>>>(x, FA2, F, XFp);
    stageC<<<512, 256, 0, stream>>>(XFp, Wr, Wi, Gp);
    fusedDE<<<512, 256, 0, stream>>>(F, Gp, GE2, out);
}

// Round 12
// 87.886 us; speedup vs baseline: 1.3675x; 1.2399x over previous
//
#include <hip/hip_runtime.h>
#include <math.h>

#define IN_CH 64
#define OUT_CH 64
#define M1 32
#define M2 32
#define HH 512
#define WW 512

// ---------------- workspace layout (floats) ----------------
// F   : [512][64]  cols 0..31 = cos(2pi k h/512), cols 32..63 = sin(...)
// FA2 : [256][64]  folded stage-A table. col j<32: re, j>=32: im; mode k=kperm(j&31);
//                  value = cos(2pi k w'/512) (re) or -sin (im). kperm(q)= q<16 ? 2q : 2(q-16)+1.
// GE2 : [64][256]  folded stage-E table. row c: c<16 re k=2c; 16..31 im k=2(c-16);
//                  32..47 re k=2(c-32)+1; 48..63 im k=2(c-48)+1. cos (re) / -sin (im).
// GT  : [64][512]  row j<32: cos(2pi j t/512); row j>=32: -sin(...)
// XFp : [64 i][8 ht][2 reim][32 kx][32 ky']  partial h-DFT
// Gp  : [2 ic][64 o][32 kx][32 ky][2]  partial channel-mix (REAL ky order)
static const size_t OFF_F   = 0;
static const size_t OFF_FA2 = 32768;
static const size_t OFF_GE2 = 49152;
static const size_t OFF_GT  = 65536;
static const size_t OFF_XFP = 98304;
static const size_t OFF_GP  = OFF_XFP + (size_t)64*8*2048;

__device__ __forceinline__ void gload16(const float* g, float* l) {
    __builtin_amdgcn_global_load_lds(
        (const __attribute__((address_space(1))) void*)g,
        (__attribute__((address_space(3))) void*)l, 16, 0, 0);
}

__global__ void build_table(float* __restrict__ F, float* __restrict__ FA2,
                            float* __restrict__ GE2, float* __restrict__ GT) {
    int idx = blockIdx.x * 256 + threadIdx.x;      // 0..32767
    const float c0 = 6.283185307179586f / 512.0f;
    {   // F + GT
        int w = idx >> 6, j = idx & 63, k = j & 31;
        int m = (k * w) & 511;
        float s, c;
        sincosf(c0 * (float)m, &s, &c);
        F[idx] = (j < 32) ? c : s;
        GT[(size_t)j * 512 + w] = (j < 32) ? c : -s;
    }
    if (idx < 16384) {   // FA2 [256][64]
        int wp = idx >> 6, j = idx & 63, q = j & 31;
        int k = (q < 16) ? 2 * q : 2 * (q - 16) + 1;
        int m = (k * wp) & 511;
        float s, c;
        sincosf(c0 * (float)m, &s, &c);
        FA2[idx] = (j < 32) ? c : -s;
    }
    if (idx < 16384) {   // GE2 [64][256]
        int cc = idx >> 8, wp = idx & 255;
        int base = cc & 15, parity = (cc >> 5) & 1, isIm = (cc >> 4) & 1;
        int k = 2 * base + parity;
        int m = (k * wp) & 511;
        float s, c;
        sincosf(c0 * (float)m, &s, &c);
        GE2[idx] = isIm ? -s : c;
    }
}

// Fused A+B, K-chunk 32, 4 blocks/CU. grid 512: i = bid>>3, ht = bid&7 (64 h-rows).
// xeo: e at cols 0..31, o at cols 36..67 of one [64][68] tile (17.4 KB);
// bs: FA2 double-buffer 2x[32][64] inside the 4352-float region phase B reuses.
// Per chunk: [syncA][write e/o from regs][syncB][issue x(tt+1)->regs + gload FA2(tt+1)]
//            [compute tt] — every load has a full compute phase before its drain.
__global__ __launch_bounds__(256, 4) void fusedAB(const float* __restrict__ x,
                                                  const float* __restrict__ FA2,
                                                  const float* __restrict__ GT,
                                                  float* __restrict__ XFp) {
    __shared__ __align__(16) float xeo[4352];   // A: e/o tile; B: xw [64][68]
    __shared__ __align__(16) float bs[4352];    // A: FA2 dbuf @0/@2048; B: gt [64][68]
    int t = threadIdx.x, tx = t & 15, ty = t >> 4;
    int i = blockIdx.x >> 3, ht = blockIdx.x & 7;
    int h0 = ht * 64;
    int srow = t >> 2, sc = (t & 3) * 8;        // staging: 4 threads/row, 8 cols each

    const float* xb = x + ((size_t)i * 512 + h0 + srow) * 512 + sc;
    float4 a0, a1, b0, b1, gtr[4];

    // prologue: x chunk0 -> regs; FA2 chunk0 -> bs[0]
    a0 = *(const float4*)(xb + 0);
    a1 = *(const float4*)(xb + 4);
    b0 = *(const float4*)(xb + 256);
    b1 = *(const float4*)(xb + 260);
    gload16(FA2 + t * 4, &bs[t * 4]);
    gload16(FA2 + 1024 + t * 4, &bs[1024 + t * 4]);

    float acc[4][4] = {};
    const float* xsb = &xeo[(tx & 4) ? 36 : 0];   // cols 16..31,48..63: odd-k -> o
    for (int tt = 0; tt < 8; ++tt) {
        if (tt) __syncthreads();     // A: readers of chunk tt-1 done
        *(float4*)&xeo[srow * 68 + sc] =
            make_float4(a0.x + b0.x, a0.y + b0.y, a0.z + b0.z, a0.w + b0.w);
        *(float4*)&xeo[srow * 68 + sc + 4] =
            make_float4(a1.x + b1.x, a1.y + b1.y, a1.z + b1.z, a1.w + b1.w);
        *(float4*)&xeo[srow * 68 + 36 + sc] =
            make_float4(a0.x - b0.x, a0.y - b0.y, a0.z - b0.z, a0.w - b0.w);
        *(float4*)&xeo[srow * 68 + 36 + sc + 4] =
            make_float4(a1.x - b1.x, a1.y - b1.y, a1.z - b1.z, a1.w - b1.w);
        __syncthreads();             // B: e/o visible; bs chunk tt drained
        int cur = (tt & 1) << 11;
        if (tt < 7) {                // issue next chunk's loads AFTER the barrier
            const float* xn = xb + (tt + 1) * 32;
            a0 = *(const float4*)(xn + 0);
            a1 = *(const float4*)(xn + 4);
            b0 = *(const float4*)(xn + 256);
            b1 = *(const float4*)(xn + 260);
            int nxt = ((tt + 1) & 1) << 11;
            gload16(FA2 + (size_t)(tt + 1) * 2048 + t * 4, &bs[nxt + t * 4]);
            gload16(FA2 + (size_t)(tt + 1) * 2048 + 1024 + t * 4, &bs[nxt + 1024 + t * 4]);
        } else {                     // prefetch GT slice for phase B into regs
#pragma unroll
            for (int p = 0; p < 4; ++p) {
                int flat = p * 1024 + t * 4;
                int j = flat >> 6, hc = flat & 63;
                gtr[p] = *(const float4*)&GT[(size_t)j * 512 + h0 + hc];
            }
        }
#pragma unroll
        for (int k0 = 0; k0 < 32; k0 += 4) {
            float4 av[4], bv[4];
#pragma unroll
            for (int r = 0; r < 4; ++r)
                av[r] = *(const float4*)&xsb[(ty * 4 + r) * 68 + k0];
#pragma unroll
            for (int kk = 0; kk < 4; ++kk)
                bv[kk] = *(const float4*)&bs[cur + (k0 + kk) * 64 + tx * 4];
#pragma unroll
            for (int kk = 0; kk < 4; ++kk)
#pragma unroll
                for (int r = 0; r < 4; ++r) {
                    float xk = (kk == 0) ? av[r].x : (kk == 1) ? av[r].y
                             : (kk == 2) ? av[r].z : av[r].w;
                    acc[r][0] = __builtin_fmaf(xk, bv[kk].x, acc[r][0]);
                    acc[r][1] = __builtin_fmaf(xk, bv[kk].y, acc[r][1]);
                    acc[r][2] = __builtin_fmaf(xk, bv[kk].z, acc[r][2]);
                    acc[r][3] = __builtin_fmaf(xk, bv[kk].w, acc[r][3]);
                }
        }
    }
    __syncthreads();

    // store Xw tile into xeo ([64][68]) and gt regs into bs ([64][68])
#pragma unroll
    for (int r = 0; r < 4; ++r)
        *(float4*)&xeo[(ty * 4 + r) * 68 + tx * 4] =
            make_float4(acc[r][0], acc[r][1], acc[r][2], acc[r][3]);
#pragma unroll
    for (int p = 0; p < 4; ++p) {
        int flat = p * 1024 + t * 4;
        int j = flat >> 6, hc = flat & 63;
        *(float4*)&bs[j * 68 + hc] = gtr[p];
    }
    __syncthreads();

    // Phase B (R7 verbatim)
    int kx = t >> 3, kg = t & 7;
    float rr[4] = {0.f, 0.f, 0.f, 0.f};
    float ii[4] = {0.f, 0.f, 0.f, 0.f};
#pragma unroll 4
    for (int hh = 0; hh < 64; ++hh) {
        float cv = bs[kx * 68 + hh];
        float sv = bs[(kx + 32) * 68 + hh];          // = -sin
        float4 xr4 = *(const float4*)&xeo[hh * 68 + kg * 4];
        float4 xi4 = *(const float4*)&xeo[hh * 68 + 32 + kg * 4];
        rr[0] = __builtin_fmaf(xr4.x, cv, rr[0]); rr[0] = __builtin_fmaf(xi4.x, -sv, rr[0]);
        rr[1] = __builtin_fmaf(xr4.y, cv, rr[1]); rr[1] = __builtin_fmaf(xi4.y, -sv, rr[1]);
        rr[2] = __builtin_fmaf(xr4.z, cv, rr[2]); rr[2] = __builtin_fmaf(xi4.z, -sv, rr[2]);
        rr[3] = __builtin_fmaf(xr4.w, cv, rr[3]); rr[3] = __builtin_fmaf(xi4.w, -sv, rr[3]);
        ii[0] = __builtin_fmaf(xi4.x, cv, ii[0]); ii[0] = __builtin_fmaf(xr4.x, sv, ii[0]);
        ii[1] = __builtin_fmaf(xi4.y, cv, ii[1]); ii[1] = __builtin_fmaf(xr4.y, sv, ii[1]);
        ii[2] = __builtin_fmaf(xi4.z, cv, ii[2]); ii[2] = __builtin_fmaf(xr4.z, sv, ii[2]);
        ii[3] = __builtin_fmaf(xi4.w, cv, ii[3]); ii[3] = __builtin_fmaf(xr4.w, sv, ii[3]);
    }
    size_t base = ((size_t)i * 8 + ht) * 2048;
    *(float4*)&XFp[base + t * 4]        = make_float4(rr[0], rr[1], rr[2], rr[3]);
    *(float4*)&XFp[base + 1024 + t * 4] = make_float4(ii[0], ii[1], ii[2], ii[3]);
}

// Stage C: partial channel mix, i split in 2. grid 512. (R7 verbatim)
__global__ __launch_bounds__(256) void stageC(const float* __restrict__ XFp,
                                              const float* __restrict__ Wr,
                                              const float* __restrict__ Wi,
                                              float* __restrict__ Gp) {
    __shared__ float sxr[32][33];   // [ky'][i']
    __shared__ float sxi[32][33];
    int t = threadIdx.x;
    int kx = blockIdx.x & 31, oc = (blockIdx.x >> 5) & 7, ic = blockIdx.x >> 8;
#pragma unroll
    for (int q = 0; q < 4; ++q) {
        int idx = q * 256 + t;               // 0..1023 = i'*32 + ky'(storage)
        int ip = idx >> 5, kys = idx & 31;
        int i = ic * 32 + ip;
        float sr = 0.f, si = 0.f;
#pragma unroll
        for (int ht = 0; ht < 8; ++ht) {
            size_t base = ((size_t)i * 8 + ht) * 2048 + kx * 32 + kys;
            sr += XFp[base];
            si += XFp[base + 1024];
        }
        sxr[kys][ip] = sr;
        sxi[kys][ip] = si;
    }
    __syncthreads();
    int ky = t & 31, ol = t >> 5;            // REAL ky
    int kyp = (ky & 1) ? 16 + (ky >> 1) : (ky >> 1);
    int o = oc * 8 + ol;
    float lr = 0.f, li = 0.f;
#pragma unroll 4
    for (int ip = 0; ip < 32; ++ip) {
        float a = sxr[kyp][ip];
        float b = sxi[kyp][ip];
        size_t widx = ((size_t)(ic * 32 + ip) * 64 + o) * 1024 + kx * 32 + ky;
        float wrv = Wr[widx];
        float wiv = Wi[widx];
        lr = __builtin_fmaf(a, wrv, lr); lr = __builtin_fmaf(-b, wiv, lr);
        li = __builtin_fmaf(a, wiv, li); li = __builtin_fmaf(b, wrv, li);
    }
    size_t gidx = ((size_t)ic * 65536 + (size_t)o * 1024 + kx * 32 + ky) * 2;
    Gp[gidx]     = lr;
    Gp[gidx + 1] = li;
}

// Fused (reduceG +) D + E. grid 512: o = bid>>3, ht = bid&7. (R7 verbatim)
__global__ __launch_bounds__(256) void fusedDE(const float* __restrict__ Fc,
                                               const float* __restrict__ Gp,
                                               const float* __restrict__ GE2,
                                               float* __restrict__ out) {
    __shared__ __align__(16) float as[4096];   // F-tile (src-swizzled), then Z (XOR-swizzled)
    __shared__ __align__(16) float bs[4096];   // G [64m][64j'], then GE2 tiles
    int t = threadIdx.x, tx = t & 15, ty = t >> 4;
    int o = blockIdx.x >> 3, ht = blockIdx.x & 7;
    int sw = (ty & 3) << 2;

    const float2* gp2 = (const float2*)Gp;
#pragma unroll
    for (int q = 0; q < 4; ++q) {
        int iq = q * 256 + t;                 // 0..1023 = kx*32+ky (REAL ky)
        int ky = iq & 31, kx = iq >> 5;
        float2 g0 = gp2[(size_t)o * 1024 + iq];
        float2 g1 = gp2[(size_t)65536 + (size_t)o * 1024 + iq];
        float sc = ((ky == 0) ? 1.0f : 2.0f) * (1.0f / 262144.0f);
        float lr = (g0.x + g1.x) * sc;
        float li = (g0.y + g1.y) * sc;
        int pp = ky & 1, qq = ky >> 1;
        int colR = pp * 32 + qq, colI = pp * 32 + 16 + qq;
        bs[kx * 64 + colR]        = lr;
        bs[(32 + kx) * 64 + colR] = -li;
        bs[kx * 64 + colI]        = li;
        bs[(32 + kx) * 64 + colI] = lr;
    }
#pragma unroll
    for (int p = 0; p < 4; ++p) {
        int flat = p * 1024 + t * 4;
        int s16 = flat >> 2;
        int row = s16 >> 4, cp = s16 & 15;
        int cg = cp ^ ((row >> 2) & 3);
        gload16(Fc + (size_t)(ht * 64 + row) * 64 + cg * 4, &as[flat]);
    }
    __syncthreads();

    float acc[4][4] = {};
#pragma unroll 4
    for (int k0 = 0; k0 < 64; k0 += 4) {
        int ka = k0 ^ sw;
        float4 av[4], bv[4];
#pragma unroll
        for (int r = 0; r < 4; ++r)
            av[r] = *(const float4*)&as[(ty * 4 + r) * 64 + ka];
#pragma unroll
        for (int kk = 0; kk < 4; ++kk)
            bv[kk] = *(const float4*)&bs[(k0 + kk) * 64 + tx * 4];
#pragma unroll
        for (int kk = 0; kk < 4; ++kk)
#pragma unroll
            for (int r = 0; r < 4; ++r) {
                float xk = (kk == 0) ? av[r].x : (kk == 1) ? av[r].y
                         : (kk == 2) ? av[r].z : av[r].w;
                acc[r][0] = __builtin_fmaf(xk, bv[kk].x, acc[r][0]);
                acc[r][1] = __builtin_fmaf(xk, bv[kk].y, acc[r][1]);
                acc[r][2] = __builtin_fmaf(xk, bv[kk].z, acc[r][2]);
                acc[r][3] = __builtin_fmaf(xk, bv[kk].w, acc[r][3]);
            }
    }
    __syncthreads();

#pragma unroll
    for (int r = 0; r < 4; ++r) {
        int row = ty * 4 + r;
        int cg = tx ^ ((row >> 2) & 3);
        *(float4*)&as[row * 64 + cg * 4] =
            make_float4(acc[r][0], acc[r][1], acc[r][2], acc[r][3]);
    }

    for (int cb = 0; cb < 4; ++cb) {
        __syncthreads();
#pragma unroll
        for (int p = 0; p < 4; ++p) {
            int flat = p * 1024 + t * 4;
            int brow = flat >> 6, bcol = flat & 63;
            gload16(GE2 + (size_t)brow * 256 + cb * 64 + bcol, &bs[flat]);
        }
        __syncthreads();
        float pa[4][4] = {}, pb[4][4] = {};
#pragma unroll 4
        for (int k0 = 0; k0 < 32; k0 += 4) {
            int kae = k0 ^ sw, kao = 32 + (k0 ^ sw);
            float4 av[4], bv[4], aw[4], bw[4];
#pragma unroll
            for (int r = 0; r < 4; ++r) {
                av[r] = *(const float4*)&as[(ty * 4 + r) * 64 + kae];
                aw[r] = *(const float4*)&as[(ty * 4 + r) * 64 + kao];
            }
#pragma unroll
            for (int kk = 0; kk < 4; ++kk) {
                bv[kk] = *(const float4*)&bs[(k0 + kk) * 64 + tx * 4];
                bw[kk] = *(const float4*)&bs[(32 + k0 + kk) * 64 + tx * 4];
            }
#pragma unroll
            for (int kk = 0; kk < 4; ++kk)
#pragma unroll
                for (int r = 0; r < 4; ++r) {
                    float xe = (kk == 0) ? av[r].x : (kk == 1) ? av[r].y
                             : (kk == 2) ? av[r].z : av[r].w;
                    float xo = (kk == 0) ? aw[r].x : (kk == 1) ? aw[r].y
                             : (kk == 2) ? aw[r].z : aw[r].w;
                    pa[r][0] = __builtin_fmaf(xe, bv[kk].x, pa[r][0]);
                    pa[r][1] = __builtin_fmaf(xe, bv[kk].y, pa[r][1]);
                    pa[r][2] = __builtin_fmaf(xe, bv[kk].z, pa[r][2]);
                    pa[r][3] = __builtin_fmaf(xe, bv[kk].w, pa[r][3]);
                    pb[r][0] = __builtin_fmaf(xo, bw[kk].x, pb[r][0]);
                    pb[r][1] = __builtin_fmaf(xo, bw[kk].y, pb[r][1]);
                    pb[r][2] = __builtin_fmaf(xo, bw[kk].z, pb[r][2]);
                    pb[r][3] = __builtin_fmaf(xo, bw[kk].w, pb[r][3]);
                }
        }
#pragma unroll
        for (int r = 0; r < 4; ++r) {
            float* orow = out + (size_t)(o * 512 + ht * 64 + ty * 4 + r) * 512;
            *(float4*)&orow[cb * 64 + tx * 4] =
                make_float4(pa[r][0] + pb[r][0], pa[r][1] + pb[r][1],
                            pa[r][2] + pb[r][2], pa[r][3] + pb[r][3]);
            *(float4*)&orow[256 + cb * 64 + tx * 4] =
                make_float4(pa[r][0] - pb[r][0], pa[r][1] - pb[r][1],
                            pa[r][2] - pb[r][2], pa[r][3] - pb[r][3]);
        }
    }
}

extern "C" void kernel_launch(void* const* d_in, const int* in_sizes, int n_in,
                              void* d_out, int out_size, void* d_ws, size_t ws_size,
                              hipStream_t stream) {
    const float* x  = (const float*)d_in[0];
    const float* Wr = (const float*)d_in[1];
    const float* Wi = (const float*)d_in[2];
    float* out = (float*)d_out;
    float* ws  = (float*)d_ws;

    float* F   = ws + OFF_F;
    float* FA2 = ws + OFF_FA2;
    float* GE2 = ws + OFF_GE2;
    float* GT  = ws + OFF_GT;
    float* XFp = ws + OFF_XFP;
    float* Gp  = ws + OFF_GP;

    build_table<<<128, 256, 0, stream>>>(F, FA2, GE2, GT);
    fusedAB<<<512, 256, 0, stream>>>(x, FA2, GT, XFp);
    stageC<<<512, 256, 0, stream>>>(XFp, Wr, Wi, Gp);
    fusedDE<<<512, 256, 0, stream>>>(F, Gp, GE2, out);
}